// Round 8
// baseline (418.814 us; speedup 1.0000x reference)
//
#include <hip/hip_runtime.h>
#include <hip/hip_bf16.h>

#define HH 16
#define DD 128
#define NBQ 128
#define SS 8192

typedef __attribute__((ext_vector_type(4))) float f32x4;
typedef __attribute__((ext_vector_type(4))) short bf16x4;
typedef __attribute__((ext_vector_type(8))) short bf16x8;

__device__ __forceinline__ unsigned short f2bf(float f) {
  unsigned u = __builtin_bit_cast(unsigned, f);
  u += 0x7fff + ((u >> 16) & 1);   // round-to-nearest-even
  return (unsigned short)(u >> 16);
}

// single-instruction HW convert (v_cvt_*_bf16): let the compiler pick the opcode
__device__ __forceinline__ short f2bf_hw(float f) {
  __hip_bfloat16 b = __float2bfloat16(f);
  return __builtin_bit_cast(short, b);
}

// ---------------- prepass 1: K fp32 [s][h][d] -> bf16 [h][s][d] ----------------
__global__ __launch_bounds__(256)
void conv_k_kernel(const float* __restrict__ kg, unsigned short* __restrict__ kb) {
  const size_t e = ((size_t)blockIdx.x * 256 + threadIdx.x) * 4;  // out element idx
  const int h = (int)(e >> 20);           // S*D = 2^20
  const int s = (int)((e >> 7) & (SS - 1));
  const int d = (int)(e & 127);
  f32x4 a = *(const f32x4*)(kg + ((size_t)s * HH + h) * DD + d);
  bf16x4 o;
  o[0] = (short)f2bf(a[0]); o[1] = (short)f2bf(a[1]);
  o[2] = (short)f2bf(a[2]); o[3] = (short)f2bf(a[3]);
  *(bf16x4*)(kb + e) = o;
}

// ------- prepass 2: V fp32 [s][h][d] -> bf16 transposed blocks [h][kb][d][64] -------
__global__ __launch_bounds__(256)
void conv_vt_kernel(const float* __restrict__ vg, unsigned short* __restrict__ vt) {
  __shared__ unsigned short tile[128 * 72];  // [d][s'] with +8 short pad per row
  const int kb = blockIdx.x, h = blockIdx.y, tid = threadIdx.x;
  {
    const int r = tid >> 2, q = tid & 3;
    const float* vp = vg + ((size_t)(kb * 64 + r) * HH + h) * DD + q * 32;
    #pragma unroll
    for (int c = 0; c < 8; ++c) {
      f32x4 a = *(const f32x4*)(vp + c * 4);
      #pragma unroll
      for (int j = 0; j < 4; ++j) tile[(q * 32 + c * 4 + j) * 72 + r] = f2bf(a[j]);
    }
  }
  __syncthreads();
  const int d = tid >> 1, half = tid & 1;
  unsigned short* op = vt + ((size_t)(h * NBQ + kb) * 128 + d) * 64 + half * 32;
  #pragma unroll
  for (int j = 0; j < 4; ++j)
    *(bf16x8*)(op + j * 8) = *(const bf16x8*)(&tile[d * 72 + half * 32 + j * 8]);
}

// ------------- main kernel: 1 workgroup = (2 q-blocks, head), 4 waves x 32 rows -------------
// v5-verified math/layout. Structural change: SINGLE K/V LDS buffer (48KB total incl. P)
// -> 3 workgroups/CU, with T14 reg-staged prefetch: global->reg issued BEFORE compute(t),
// reg->LDS (swizzled ds_write_b128) between two barriers after compute. P conversion via
// single-op HW cvt. Softmax: exp2-domain, defer-max THR=8, deferred sum.
#define SWK(o) ((o) ^ ((((o) >> 8) & 7) << 4))
#define SWV(o) ((o) ^ ((((o) >> 7) & 7) << 4))

__global__ __launch_bounds__(256, 3)
void sparse_attn_v7(const float* __restrict__ qg_, const unsigned short* __restrict__ kbuf,
                    const unsigned short* __restrict__ vtbuf, float* __restrict__ outg) {
  extern __shared__ __align__(16) char lds[];
  // K [64 key][128 d] bf16 swz at 0 (16KB) | Vt [128 d][64 key] swz at 16384 (16KB)
  // P per-wave: 32768 + wid*4096 ([32 row][64 key] bf16 swz)  => total 48KB

  const int qgrp = blockIdx.x;   // 0..63
  const int h    = blockIdx.y;
  const int tid  = threadIdx.x;
  const int wid  = tid >> 6;
  const int lane = tid & 63;
  const int l15  = lane & 15;
  const int lg   = lane >> 4;

  const int qlo  = qgrp * 2, qhi = qgrp * 2 + 1;
  const int qb_w = qlo + (wid >> 1);          // this wave's q-block
  const int rib0 = (wid & 1) * 32;            // wave's row base within its q-block

  const int nv     = (qhi + 1 < 4) ? qhi + 1 : 4;
  const int wstart = (qlo - 3 > 4) ? qlo - 3 : 4;
  const int nw     = (qhi - wstart + 1 > 0) ? qhi - wstart + 1 : 0;
  const int nlist  = nv + nw;

  char* Ks = lds;
  char* Vs = lds + 16384;
  char* Pl = lds + 32768 + wid * 4096;
  // 1/sqrt(128) * log2(e): exp2-domain softmax
  const float scale = 0.12752030522080552f;

  // ---- Q fragments (A operand), scale folded ----
  bf16x8 qa[2][4];
  #pragma unroll
  for (int m = 0; m < 2; ++m) {
    const float* qp = qg_ + ((size_t)(qgrp * 128 + wid * 32 + m * 16 + l15) * HH + h) * DD;
    #pragma unroll
    for (int kc = 0; kc < 4; ++kc) {
      const int d0 = kc * 32 + lg * 8;
      f32x4 a = *(const f32x4*)(qp + d0);
      f32x4 b = *(const f32x4*)(qp + d0 + 4);
      bf16x8 f;
      f[0] = f2bf_hw(a[0] * scale); f[1] = f2bf_hw(a[1] * scale);
      f[2] = f2bf_hw(a[2] * scale); f[3] = f2bf_hw(a[3] * scale);
      f[4] = f2bf_hw(b[0] * scale); f[5] = f2bf_hw(b[1] * scale);
      f[6] = f2bf_hw(b[2] * scale); f[7] = f2bf_hw(b[3] * scale);
      qa[m][kc] = f;
    }
  }

  f32x4 oa[2][8];
  #pragma unroll
  for (int m = 0; m < 2; ++m)
    #pragma unroll
    for (int i = 0; i < 8; ++i) oa[m][i] = (f32x4){0.f, 0.f, 0.f, 0.f};
  float mr[2][4], lr[2][4];   // mr: row-uniform running max; lr: per-lane PARTIAL sum
  #pragma unroll
  for (int m = 0; m < 2; ++m)
    #pragma unroll
    for (int r = 0; r < 4; ++r) { mr[m][r] = -1e30f; lr[m][r] = 0.f; }

  const char* kbase = (const char*)kbuf + ((size_t)h * NBQ << 14);
  const char* vbase = (const char*)vtbuf + ((size_t)h * NBQ << 14);
  const int o0 = wid * 1024 + lane * 16;   // this thread's 16B slot in each 4KB round

  // ---- prologue: stage list[0] (= block 0) via reg path ----
  {
    uint4 k0 = *(const uint4*)(kbase + o0);
    uint4 k1 = *(const uint4*)(kbase + o0 + 4096);
    uint4 k2 = *(const uint4*)(kbase + o0 + 8192);
    uint4 k3 = *(const uint4*)(kbase + o0 + 12288);
    uint4 v0 = *(const uint4*)(vbase + o0);
    uint4 v1 = *(const uint4*)(vbase + o0 + 4096);
    uint4 v2 = *(const uint4*)(vbase + o0 + 8192);
    uint4 v3 = *(const uint4*)(vbase + o0 + 12288);
    *(uint4*)(Ks + SWK(o0))         = k0;
    *(uint4*)(Ks + SWK(o0 + 4096))  = k1;
    *(uint4*)(Ks + SWK(o0 + 8192))  = k2;
    *(uint4*)(Ks + SWK(o0 + 12288)) = k3;
    *(uint4*)(Vs + SWV(o0))         = v0;
    *(uint4*)(Vs + SWV(o0 + 4096))  = v1;
    *(uint4*)(Vs + SWV(o0 + 8192))  = v2;
    *(uint4*)(Vs + SWV(o0 + 12288)) = v3;
  }
  __syncthreads();

  for (int t = 0; t < nlist; ++t) {
    const int  kb       = (t < nv) ? t : (wstart + (t - nv));
    const bool havenext = (t + 1 < nlist);

    // ---- issue next tile's global loads into regs (latency hidden under compute) ----
    uint4 k0, k1, k2, k3, v0, v1, v2, v3;
    if (havenext) {
      const int kbn = (t + 1 < nv) ? (t + 1) : (wstart + (t + 1 - nv));
      const char* ks = kbase + ((size_t)kbn << 14);
      const char* vs = vbase + ((size_t)kbn << 14);
      k0 = *(const uint4*)(ks + o0);
      k1 = *(const uint4*)(ks + o0 + 4096);
      k2 = *(const uint4*)(ks + o0 + 8192);
      k3 = *(const uint4*)(ks + o0 + 12288);
      v0 = *(const uint4*)(vs + o0);
      v1 = *(const uint4*)(vs + o0 + 4096);
      v2 = *(const uint4*)(vs + o0 + 8192);
      v3 = *(const uint4*)(vs + o0 + 12288);
    }

    const bool valid = (kb <= qb_w) && ((qb_w - kb < 4) || (kb < 4));
    if (valid) {
      // ---- S = Q K^T : row q = lg*4+r, col key = n4*16+l15 (v2-verified) ----
      f32x4 s[2][4];
      #pragma unroll
      for (int m = 0; m < 2; ++m)
        #pragma unroll
        for (int n4 = 0; n4 < 4; ++n4) s[m][n4] = (f32x4){0.f, 0.f, 0.f, 0.f};
      __builtin_amdgcn_s_setprio(1);
      #pragma unroll
      for (int n4 = 0; n4 < 4; ++n4) {
        const int key = n4 * 16 + l15;
        #pragma unroll
        for (int kc = 0; kc < 4; ++kc) {
          const int off = (key * 256 + (kc * 32 + lg * 8) * 2) ^ ((key & 7) << 4);
          bf16x8 kf = *(const bf16x8*)(Ks + off);
          s[0][n4] = __builtin_amdgcn_mfma_f32_16x16x32_bf16(qa[0][kc], kf, s[0][n4], 0, 0, 0);
          s[1][n4] = __builtin_amdgcn_mfma_f32_16x16x32_bf16(qa[1][kc], kf, s[1][n4], 0, 0, 0);
        }
      }
      __builtin_amdgcn_s_setprio(0);

      // ---- diagonal block: element-level causal mask ----
      if (kb == qb_w) {
        #pragma unroll
        for (int m = 0; m < 2; ++m)
          #pragma unroll
          for (int n4 = 0; n4 < 4; ++n4) {
            const int key = n4 * 16 + l15;
            #pragma unroll
            for (int r = 0; r < 4; ++r) {
              const int rib = rib0 + m * 16 + lg * 4 + r;
              if (rib < key) s[m][n4][r] = -1e30f;
            }
          }
      }

      // ---- softmax: exp2 domain, defer-max THR=8, deferred sum ----
      #pragma unroll
      for (int m = 0; m < 2; ++m) {
        float pmax[4];
        #pragma unroll
        for (int r = 0; r < 4; ++r)
          pmax[r] = fmaxf(fmaxf(s[m][0][r], s[m][1][r]), fmaxf(s[m][2][r], s[m][3][r]));
        const int ok = (pmax[0] <= mr[m][0] + 8.f) & (pmax[1] <= mr[m][1] + 8.f) &
                       (pmax[2] <= mr[m][2] + 8.f) & (pmax[3] <= mr[m][3] + 8.f);
        if (!__all(ok)) {
          float sc[4];
          #pragma unroll
          for (int r = 0; r < 4; ++r) {
            float mx = pmax[r];
            mx = fmaxf(mx, __shfl_xor(mx, 1));
            mx = fmaxf(mx, __shfl_xor(mx, 2));
            mx = fmaxf(mx, __shfl_xor(mx, 4));
            mx = fmaxf(mx, __shfl_xor(mx, 8));   // row-uniform across l15
            const float mnew = fmaxf(mr[m][r], mx);
            sc[r] = __builtin_amdgcn_exp2f(mr[m][r] - mnew);
            mr[m][r] = mnew;
            lr[m][r] *= sc[r];                   // partial sums scale too
          }
          #pragma unroll
          for (int nd = 0; nd < 8; ++nd) {
            oa[m][nd][0] *= sc[0]; oa[m][nd][1] *= sc[1];
            oa[m][nd][2] *= sc[2]; oa[m][nd][3] *= sc[3];
          }
        }
        #pragma unroll
        for (int r = 0; r < 4; ++r) {
          float acc = 0.f;
          #pragma unroll
          for (int n4 = 0; n4 < 4; ++n4) {
            const float p = __builtin_amdgcn_exp2f(s[m][n4][r] - mr[m][r]);
            s[m][n4][r] = p;
            acc += p;
          }
          lr[m][r] += acc;   // lane-partial: no shuffles here
        }
      }

      // ---- P -> per-wave LDS (bf16 via HW cvt, swz) for A-fragment transpose ----
      #pragma unroll
      for (int m = 0; m < 2; ++m)
        #pragma unroll
        for (int n4 = 0; n4 < 4; ++n4) {
          const int col = n4 * 16 + l15;
          #pragma unroll
          for (int r = 0; r < 4; ++r) {
            const int row = m * 16 + lg * 4 + r;
            const int off = (row * 128 + col * 2) ^ ((row & 7) << 4);
            *(short*)(Pl + off) = f2bf_hw(s[m][n4][r]);
          }
        }
      bf16x8 pa[2][2];
      #pragma unroll
      for (int m = 0; m < 2; ++m) {
        const int row = m * 16 + l15;
        #pragma unroll
        for (int kc = 0; kc < 2; ++kc) {
          const int off = (row * 128 + (kc * 32 + lg * 8) * 2) ^ ((row & 7) << 4);
          pa[m][kc] = *(const bf16x8*)(Pl + off);
        }
      }

      // ---- O += P V ----
      __builtin_amdgcn_s_setprio(1);
      #pragma unroll
      for (int nd = 0; nd < 8; ++nd) {
        const int d = nd * 16 + l15;
        #pragma unroll
        for (int kc = 0; kc < 2; ++kc) {
          const int off = (d * 128 + (kc * 32 + lg * 8) * 2) ^ ((d & 7) << 4);
          bf16x8 vf = *(const bf16x8*)(Vs + off);
          oa[0][nd] = __builtin_amdgcn_mfma_f32_16x16x32_bf16(pa[0][kc], vf, oa[0][nd], 0, 0, 0);
          oa[1][nd] = __builtin_amdgcn_mfma_f32_16x16x32_bf16(pa[1][kc], vf, oa[1][nd], 0, 0, 0);
        }
      }
      __builtin_amdgcn_s_setprio(0);
    }

    __syncthreads();   // barrier 1: all waves done READING Ks/Vs for tile t
    if (havenext) {    // reg -> LDS (compiler inserts the vmcnt wait; loads had full compute to land)
      *(uint4*)(Ks + SWK(o0))         = k0;
      *(uint4*)(Ks + SWK(o0 + 4096))  = k1;
      *(uint4*)(Ks + SWK(o0 + 8192))  = k2;
      *(uint4*)(Ks + SWK(o0 + 12288)) = k3;
      *(uint4*)(Vs + SWV(o0))         = v0;
      *(uint4*)(Vs + SWV(o0 + 4096))  = v1;
      *(uint4*)(Vs + SWV(o0 + 8192))  = v2;
      *(uint4*)(Vs + SWV(o0 + 12288)) = v3;
    }
    __syncthreads();   // barrier 2: tile t+1 fully written
  }

  // ---- epilogue: one sum-reduction per row, normalize, store fp32 ----
  #pragma unroll
  for (int m = 0; m < 2; ++m) {
    float inv[4];
    #pragma unroll
    for (int r = 0; r < 4; ++r) {
      float l = lr[m][r];
      l += __shfl_xor(l, 1);
      l += __shfl_xor(l, 2);
      l += __shfl_xor(l, 4);
      l += __shfl_xor(l, 8);
      inv[r] = 1.0f / l;
    }
    float* op = outg + ((size_t)(qgrp * 128 + wid * 32 + m * 16) * HH + h) * DD;
    #pragma unroll
    for (int nd = 0; nd < 8; ++nd) {
      const int d = nd * 16 + l15;
      #pragma unroll
      for (int r = 0; r < 4; ++r) {
        const int qr = lg * 4 + r;
        op[(size_t)qr * HH * DD + d] = oa[m][nd][r] * inv[r];
      }
    }
  }
}

extern "C" void kernel_launch(void* const* d_in, const int* in_sizes, int n_in,
                              void* d_out, int out_size, void* d_ws, size_t ws_size,
                              hipStream_t stream) {
  const float* q = (const float*)d_in[0];
  const float* k = (const float*)d_in[1];
  const float* v = (const float*)d_in[2];
  float* out = (float*)d_out;
  const size_t elems = (size_t)HH * SS * DD;
  unsigned short* kbuf  = (unsigned short*)d_ws;
  unsigned short* vtbuf = kbuf + elems;

  conv_k_kernel<<<(int)(elems / 4 / 256), 256, 0, stream>>>(k, kbuf);
  conv_vt_kernel<<<dim3(NBQ, HH), 256, 0, stream>>>(v, vtbuf);
  sparse_attn_v7<<<dim3(NBQ / 2, HH), 256, 49152, stream>>>(q, kbuf, vtbuf, out);
}

// Round 9
// 189.378 us; speedup vs baseline: 2.2115x; 2.2115x over previous
//
#include <hip/hip_runtime.h>
#include <hip/hip_bf16.h>

#define HH 16
#define DD 128
#define NBQ 128
#define SS 8192

typedef __attribute__((ext_vector_type(4))) float f32x4;
typedef __attribute__((ext_vector_type(4))) short bf16x4;
typedef __attribute__((ext_vector_type(8))) short bf16x8;

// single-instruction HW convert (RNE), per m240: scalar cast beats hand bit-twiddle
__device__ __forceinline__ short f2bf_hw(float f) {
  __hip_bfloat16 b = __float2bfloat16(f);
  return __builtin_bit_cast(short, b);
}

__device__ __forceinline__ void gload_lds16(const void* g, void* l) {
  __builtin_amdgcn_global_load_lds(
      (const __attribute__((address_space(1))) void*)g,
      (__attribute__((address_space(3))) void*)l, 16, 0, 0);
}

// ---- fused prepass: per (kb,h) block: K fp32->bf16 [h][s][d]  AND  V -> bf16 Vt [h][kb][d][64] ----
__global__ __launch_bounds__(256)
void conv_kv_kernel(const float* __restrict__ kg, const float* __restrict__ vg,
                    unsigned short* __restrict__ kbuf, unsigned short* __restrict__ vt) {
  __shared__ unsigned short tile[128 * 72];  // [d][s'] with +8 short pad per row
  const int kb = blockIdx.x, h = blockIdx.y, tid = threadIdx.x;
  const int r = tid >> 2, q = tid & 3;
  // ---- K convert (row r, d-chunk q*32..+31) ----
  {
    const float* kp = kg + ((size_t)(kb * 64 + r) * HH + h) * DD + q * 32;
    unsigned short* ko = kbuf + ((size_t)h * SS + (size_t)kb * 64 + r) * DD + q * 32;
    #pragma unroll
    for (int c = 0; c < 4; ++c) {
      f32x4 a = *(const f32x4*)(kp + c * 8);
      f32x4 b = *(const f32x4*)(kp + c * 8 + 4);
      bf16x8 f;
      f[0] = f2bf_hw(a[0]); f[1] = f2bf_hw(a[1]); f[2] = f2bf_hw(a[2]); f[3] = f2bf_hw(a[3]);
      f[4] = f2bf_hw(b[0]); f[5] = f2bf_hw(b[1]); f[6] = f2bf_hw(b[2]); f[7] = f2bf_hw(b[3]);
      *(bf16x8*)(ko + c * 8) = f;
    }
  }
  // ---- V transpose into LDS tile ----
  {
    const float* vp = vg + ((size_t)(kb * 64 + r) * HH + h) * DD + q * 32;
    #pragma unroll
    for (int c = 0; c < 8; ++c) {
      f32x4 a = *(const f32x4*)(vp + c * 4);
      #pragma unroll
      for (int j = 0; j < 4; ++j)
        tile[(q * 32 + c * 4 + j) * 72 + r] = (unsigned short)f2bf_hw(a[j]);
    }
  }
  __syncthreads();
  const int d = tid >> 1, half = tid & 1;
  unsigned short* op = vt + ((size_t)(h * NBQ + kb) * 128 + d) * 64 + half * 32;
  #pragma unroll
  for (int j = 0; j < 4; ++j)
    *(bf16x8*)(op + j * 8) = *(const bf16x8*)(&tile[d * 72 + half * 32 + j * 8]);
}

// ------------- main kernel: 1 workgroup = (2 q-blocks, head), 4 waves x 32 rows -------------
// v5-verified math/layout. Change vs v5: V is NOT staged in LDS. PV B-fragments are loaded
// directly from the L2/L3-resident Vt buffer into registers, in two 8-load batches whose
// latency hides under softmax / P-roundtrip. K keeps the gload_lds double-buffer. LDS 48KB.
#define SWK(o) ((o) ^ ((((o) >> 8) & 7) << 4))

__global__ __launch_bounds__(256, 2)
void sparse_attn_v8(const float* __restrict__ qg_, const unsigned short* __restrict__ kbuf,
                    const unsigned short* __restrict__ vtbuf, float* __restrict__ outg) {
  extern __shared__ __align__(16) char lds[];
  // K buf b (b=0,1): b*16384, [64 key][128 d] bf16 swz | P per-wave: 32768 + wid*4096

  const int qgrp = blockIdx.x;   // 0..63
  const int h    = blockIdx.y;
  const int tid  = threadIdx.x;
  const int wid  = tid >> 6;
  const int lane = tid & 63;
  const int l15  = lane & 15;
  const int lg   = lane >> 4;

  const int qlo  = qgrp * 2, qhi = qgrp * 2 + 1;
  const int qb_w = qlo + (wid >> 1);          // this wave's q-block
  const int rib0 = (wid & 1) * 32;            // wave's row base within its q-block

  const int nv     = (qhi + 1 < 4) ? qhi + 1 : 4;
  const int wstart = (qlo - 3 > 4) ? qlo - 3 : 4;
  const int nw     = (qhi - wstart + 1 > 0) ? qhi - wstart + 1 : 0;
  const int nlist  = nv + nw;

  char* Pl = lds + 32768 + wid * 4096;
  // 1/sqrt(128) * log2(e): exp2-domain softmax
  const float scale = 0.12752030522080552f;

  // ---- Q fragments (A operand), scale folded ----
  bf16x8 qa[2][4];
  #pragma unroll
  for (int m = 0; m < 2; ++m) {
    const float* qp = qg_ + ((size_t)(qgrp * 128 + wid * 32 + m * 16 + l15) * HH + h) * DD;
    #pragma unroll
    for (int kc = 0; kc < 4; ++kc) {
      const int d0 = kc * 32 + lg * 8;
      f32x4 a = *(const f32x4*)(qp + d0);
      f32x4 b = *(const f32x4*)(qp + d0 + 4);
      bf16x8 f;
      f[0] = f2bf_hw(a[0] * scale); f[1] = f2bf_hw(a[1] * scale);
      f[2] = f2bf_hw(a[2] * scale); f[3] = f2bf_hw(a[3] * scale);
      f[4] = f2bf_hw(b[0] * scale); f[5] = f2bf_hw(b[1] * scale);
      f[6] = f2bf_hw(b[2] * scale); f[7] = f2bf_hw(b[3] * scale);
      qa[m][kc] = f;
    }
  }

  f32x4 oa[2][8];
  #pragma unroll
  for (int m = 0; m < 2; ++m)
    #pragma unroll
    for (int i = 0; i < 8; ++i) oa[m][i] = (f32x4){0.f, 0.f, 0.f, 0.f};
  float mr[2][4], lr[2][4];   // mr: row-uniform running max; lr: per-lane PARTIAL sum
  #pragma unroll
  for (int m = 0; m < 2; ++m)
    #pragma unroll
    for (int r = 0; r < 4; ++r) { mr[m][r] = -1e30f; lr[m][r] = 0.f; }

  const char* kbase = (const char*)kbuf + ((size_t)h * NBQ << 14);
  const char* vbase = (const char*)vtbuf + ((size_t)h * NBQ << 14);

  // prologue: stage K of list[0] (= block 0) into buf 0
  {
    #pragma unroll
    for (int p = 0; p < 4; ++p) {
      const int ob = p * 4096 + wid * 1024;
      const int o  = ob + lane * 16;
      gload_lds16(kbase + SWK(o), lds + ob);
    }
  }
  __syncthreads();

  for (int t = 0; t < nlist; ++t) {
    // ---- prefetch K(t+1) into the other buffer ----
    if (t + 1 < nlist) {
      const int kbn = (t + 1 < nv) ? (t + 1) : (wstart + (t + 1 - nv));
      const char* ksrc = kbase + ((size_t)kbn << 14);
      char* Kd = lds + ((t + 1) & 1) * 16384;
      #pragma unroll
      for (int p = 0; p < 4; ++p) {
        const int ob = p * 4096 + wid * 1024;
        const int o  = ob + lane * 16;
        gload_lds16(ksrc + SWK(o), Kd + ob);
      }
    }

    const int kb = (t < nv) ? t : (wstart + (t - nv));
    const bool valid = (kb <= qb_w) && ((qb_w - kb < 4) || (kb < 4));
    if (valid) {
      char* Kb = lds + (t & 1) * 16384;
      const char* vtile = vbase + ((size_t)kb << 14);

      // ---- S = Q K^T : row q = lg*4+r, col key = n4*16+l15 (v2-verified) ----
      f32x4 s[2][4];
      #pragma unroll
      for (int m = 0; m < 2; ++m)
        #pragma unroll
        for (int n4 = 0; n4 < 4; ++n4) s[m][n4] = (f32x4){0.f, 0.f, 0.f, 0.f};
      __builtin_amdgcn_s_setprio(1);
      #pragma unroll
      for (int n4 = 0; n4 < 4; ++n4) {
        const int key = n4 * 16 + l15;
        #pragma unroll
        for (int kc = 0; kc < 4; ++kc) {
          const int off = (key * 256 + (kc * 32 + lg * 8) * 2) ^ ((key & 7) << 4);
          bf16x8 kf = *(const bf16x8*)(Kb + off);
          s[0][n4] = __builtin_amdgcn_mfma_f32_16x16x32_bf16(qa[0][kc], kf, s[0][n4], 0, 0, 0);
          s[1][n4] = __builtin_amdgcn_mfma_f32_16x16x32_bf16(qa[1][kc], kf, s[1][n4], 0, 0, 0);
        }
      }
      __builtin_amdgcn_s_setprio(0);

      // ---- issue V batch 1 (nd 0..3) — latency hides under mask+softmax+P ----
      uint4 vf0[4][2];
      #pragma unroll
      for (int nd = 0; nd < 4; ++nd)
        #pragma unroll
        for (int kc = 0; kc < 2; ++kc)
          vf0[nd][kc] = *(const uint4*)(vtile + (nd * 16 + l15) * 128 + (kc * 32 + lg * 8) * 2);

      // ---- diagonal block: element-level causal mask ----
      if (kb == qb_w) {
        #pragma unroll
        for (int m = 0; m < 2; ++m)
          #pragma unroll
          for (int n4 = 0; n4 < 4; ++n4) {
            const int key = n4 * 16 + l15;
            #pragma unroll
            for (int r = 0; r < 4; ++r) {
              const int rib = rib0 + m * 16 + lg * 4 + r;
              if (rib < key) s[m][n4][r] = -1e30f;
            }
          }
      }

      // ---- softmax: exp2 domain, defer-max THR=8, deferred sum ----
      #pragma unroll
      for (int m = 0; m < 2; ++m) {
        float pmax[4];
        #pragma unroll
        for (int r = 0; r < 4; ++r)
          pmax[r] = fmaxf(fmaxf(s[m][0][r], s[m][1][r]), fmaxf(s[m][2][r], s[m][3][r]));
        const int ok = (pmax[0] <= mr[m][0] + 8.f) & (pmax[1] <= mr[m][1] + 8.f) &
                       (pmax[2] <= mr[m][2] + 8.f) & (pmax[3] <= mr[m][3] + 8.f);
        if (!__all(ok)) {
          float sc[4];
          #pragma unroll
          for (int r = 0; r < 4; ++r) {
            float mx = pmax[r];
            mx = fmaxf(mx, __shfl_xor(mx, 1));
            mx = fmaxf(mx, __shfl_xor(mx, 2));
            mx = fmaxf(mx, __shfl_xor(mx, 4));
            mx = fmaxf(mx, __shfl_xor(mx, 8));   // row-uniform across l15
            const float mnew = fmaxf(mr[m][r], mx);
            sc[r] = __builtin_amdgcn_exp2f(mr[m][r] - mnew);
            mr[m][r] = mnew;
            lr[m][r] *= sc[r];                   // partial sums scale too
          }
          #pragma unroll
          for (int nd = 0; nd < 8; ++nd) {
            oa[m][nd][0] *= sc[0]; oa[m][nd][1] *= sc[1];
            oa[m][nd][2] *= sc[2]; oa[m][nd][3] *= sc[3];
          }
        }
        #pragma unroll
        for (int r = 0; r < 4; ++r) {
          float acc = 0.f;
          #pragma unroll
          for (int n4 = 0; n4 < 4; ++n4) {
            const float p = __builtin_amdgcn_exp2f(s[m][n4][r] - mr[m][r]);
            s[m][n4][r] = p;
            acc += p;
          }
          lr[m][r] += acc;   // lane-partial: no shuffles here
        }
      }

      // ---- issue V batch 2 (nd 4..7) — hides under P-roundtrip + PV first half ----
      uint4 vf1[4][2];
      #pragma unroll
      for (int nd = 0; nd < 4; ++nd)
        #pragma unroll
        for (int kc = 0; kc < 2; ++kc)
          vf1[nd][kc] = *(const uint4*)(vtile + ((nd + 4) * 16 + l15) * 128 + (kc * 32 + lg * 8) * 2);

      // ---- P -> per-wave LDS (bf16 via HW cvt, swz) for A-fragment transpose ----
      #pragma unroll
      for (int m = 0; m < 2; ++m)
        #pragma unroll
        for (int n4 = 0; n4 < 4; ++n4) {
          const int col = n4 * 16 + l15;
          #pragma unroll
          for (int r = 0; r < 4; ++r) {
            const int row = m * 16 + lg * 4 + r;
            const int off = (row * 128 + col * 2) ^ ((row & 7) << 4);
            *(short*)(Pl + off) = f2bf_hw(s[m][n4][r]);
          }
        }
      bf16x8 pa[2][2];
      #pragma unroll
      for (int m = 0; m < 2; ++m) {
        const int row = m * 16 + l15;
        #pragma unroll
        for (int kc = 0; kc < 2; ++kc) {
          const int off = (row * 128 + (kc * 32 + lg * 8) * 2) ^ ((row & 7) << 4);
          pa[m][kc] = *(const bf16x8*)(Pl + off);
        }
      }

      // ---- O += P V  (V fragments from registers) ----
      __builtin_amdgcn_s_setprio(1);
      #pragma unroll
      for (int nd = 0; nd < 8; ++nd) {
        #pragma unroll
        for (int kc = 0; kc < 2; ++kc) {
          bf16x8 vfr = __builtin_bit_cast(bf16x8, (nd < 4) ? vf0[nd][kc] : vf1[nd - 4][kc]);
          oa[0][nd] = __builtin_amdgcn_mfma_f32_16x16x32_bf16(pa[0][kc], vfr, oa[0][nd], 0, 0, 0);
          oa[1][nd] = __builtin_amdgcn_mfma_f32_16x16x32_bf16(pa[1][kc], vfr, oa[1][nd], 0, 0, 0);
        }
      }
      __builtin_amdgcn_s_setprio(0);
    }
    __syncthreads();  // drains K prefetch vmcnt AND protects K buffer reuse
  }

  // ---- epilogue: one sum-reduction per row, normalize, store fp32 ----
  #pragma unroll
  for (int m = 0; m < 2; ++m) {
    float inv[4];
    #pragma unroll
    for (int r = 0; r < 4; ++r) {
      float l = lr[m][r];
      l += __shfl_xor(l, 1);
      l += __shfl_xor(l, 2);
      l += __shfl_xor(l, 4);
      l += __shfl_xor(l, 8);
      inv[r] = 1.0f / l;
    }
    float* op = outg + ((size_t)(qgrp * 128 + wid * 32 + m * 16) * HH + h) * DD;
    #pragma unroll
    for (int nd = 0; nd < 8; ++nd) {
      const int d = nd * 16 + l15;
      #pragma unroll
      for (int r = 0; r < 4; ++r) {
        const int qr = lg * 4 + r;
        op[(size_t)qr * HH * DD + d] = oa[m][nd][r] * inv[r];
      }
    }
  }
}

extern "C" void kernel_launch(void* const* d_in, const int* in_sizes, int n_in,
                              void* d_out, int out_size, void* d_ws, size_t ws_size,
                              hipStream_t stream) {
  const float* q = (const float*)d_in[0];
  const float* k = (const float*)d_in[1];
  const float* v = (const float*)d_in[2];
  float* out = (float*)d_out;
  const size_t elems = (size_t)HH * SS * DD;
  unsigned short* kbuf  = (unsigned short*)d_ws;
  unsigned short* vtbuf = kbuf + elems;

  conv_kv_kernel<<<dim3(NBQ, HH), 256, 0, stream>>>(k, v, kbuf, vtbuf);
  sparse_attn_v8<<<dim3(NBQ / 2, HH), 256, 49152, stream>>>(q, kbuf, vtbuf, out);
}

// Round 10
// 116.593 us; speedup vs baseline: 3.5921x; 1.6243x over previous
//
#include <hip/hip_runtime.h>
#include <hip/hip_bf16.h>

#define HH 16
#define DD 128
#define NBQ 128
#define SS 8192

typedef __attribute__((ext_vector_type(4))) float f32x4;
typedef __attribute__((ext_vector_type(4))) short bf16x4;
typedef __attribute__((ext_vector_type(8))) short bf16x8;

// single-instruction HW convert (RNE)
__device__ __forceinline__ short f2bf_hw(float f) {
  __hip_bfloat16 b = __float2bfloat16(f);
  return __builtin_bit_cast(short, b);
}

__device__ __forceinline__ void gload_lds16(const void* g, void* l) {
  __builtin_amdgcn_global_load_lds(
      (const __attribute__((address_space(1))) void*)g,
      (__attribute__((address_space(3))) void*)l, 16, 0, 0);
}

// ---------------- prepass 1: K fp32 [s][h][d] -> bf16 [h][s][d] ----------------
__global__ __launch_bounds__(256)
void conv_k_kernel(const float* __restrict__ kg, unsigned short* __restrict__ kb) {
  const size_t e = ((size_t)blockIdx.x * 256 + threadIdx.x) * 4;  // out element idx
  const int h = (int)(e >> 20);           // S*D = 2^20
  const int s = (int)((e >> 7) & (SS - 1));
  const int d = (int)(e & 127);
  f32x4 a = *(const f32x4*)(kg + ((size_t)s * HH + h) * DD + d);
  bf16x4 o;
  o[0] = f2bf_hw(a[0]); o[1] = f2bf_hw(a[1]);
  o[2] = f2bf_hw(a[2]); o[3] = f2bf_hw(a[3]);
  *(bf16x4*)(kb + e) = o;
}

// ------- prepass 2: V fp32 [s][h][d] -> bf16 transposed blocks [h][kb][d][64] -------
__global__ __launch_bounds__(256)
void conv_vt_kernel(const float* __restrict__ vg, unsigned short* __restrict__ vt) {
  __shared__ unsigned short tile[128 * 72];  // [d][s'] with +8 short pad per row
  const int kb = blockIdx.x, h = blockIdx.y, tid = threadIdx.x;
  {
    const int r = tid >> 2, q = tid & 3;
    const float* vp = vg + ((size_t)(kb * 64 + r) * HH + h) * DD + q * 32;
    #pragma unroll
    for (int c = 0; c < 8; ++c) {
      f32x4 a = *(const f32x4*)(vp + c * 4);
      #pragma unroll
      for (int j = 0; j < 4; ++j)
        tile[(q * 32 + c * 4 + j) * 72 + r] = (unsigned short)f2bf_hw(a[j]);
    }
  }
  __syncthreads();
  const int d = tid >> 1, half = tid & 1;
  unsigned short* op = vt + ((size_t)(h * NBQ + kb) * 128 + d) * 64 + half * 32;
  #pragma unroll
  for (int j = 0; j < 4; ++j)
    *(bf16x8*)(op + j * 8) = *(const bf16x8*)(&tile[d * 72 + half * 32 + j * 8]);
}

// ------------- main kernel: 1 workgroup = (2 q-blocks, head), 4 waves x 32 rows -------------
// SWAPPED QK^T: S^T = mfma_16x16x32(K-frag, Q-frag) -> lane holds q-row = l15,
// keys kt*16 + lg*4 + r in regs. P stays IN REGISTER: pack s[kt][0..3] (4 bf16 = 2 regs)
// = exact A-fragment of mfma_f32_16x16x16bf16_1k (A: row=l15, k=lg*4+{0..3}).
// PV: 4 K-steps of 16x16x16; V read as b64 B-frags from swizzled Vt LDS. Zero P-LDS traffic.
// Softmax keyed by l15 (in-lane max tree; sum is lane-partial, reduced once at end);
// row-uniform scalars transposed to oa rows (lg*4+r) via __shfl from lane lg*4+r.
#define SWK(o) ((o) ^ ((((o) >> 8) & 7) << 4))
#define SWV(o) ((o) ^ ((((o) >> 7) & 7) << 4))

__global__ __launch_bounds__(256, 2)
void sparse_attn_v9(const float* __restrict__ qg_, const unsigned short* __restrict__ kbuf,
                    const unsigned short* __restrict__ vtbuf, float* __restrict__ outg) {
  extern __shared__ __align__(16) char lds[];
  // buf b (b=0,1): K at b*32768 ([64 key][128 d] bf16 swz) | Vt at +16384 ([128 d][64 key] swz)

  const int qgrp = blockIdx.x;   // 0..63
  const int h    = blockIdx.y;
  const int tid  = threadIdx.x;
  const int wid  = tid >> 6;
  const int lane = tid & 63;
  const int l15  = lane & 15;
  const int lg   = lane >> 4;

  const int qlo  = qgrp * 2, qhi = qgrp * 2 + 1;
  const int qb_w = qlo + (wid >> 1);          // this wave's q-block
  const int rib0 = (wid & 1) * 32;            // wave's row base within its q-block

  const int nv     = (qhi + 1 < 4) ? qhi + 1 : 4;
  const int wstart = (qlo - 3 > 4) ? qlo - 3 : 4;
  const int nw     = (qhi - wstart + 1 > 0) ? qhi - wstart + 1 : 0;
  const int nlist  = nv + nw;

  // 1/sqrt(128) * log2(e): exp2-domain softmax
  const float scale = 0.12752030522080552f;

  // ---- Q fragments (B operand: col j = q-row = l15, k = d = kc*32+lg*8+{0..7}) ----
  bf16x8 qa[2][4];
  #pragma unroll
  for (int m = 0; m < 2; ++m) {
    const float* qp = qg_ + ((size_t)(qgrp * 128 + wid * 32 + m * 16 + l15) * HH + h) * DD;
    #pragma unroll
    for (int kc = 0; kc < 4; ++kc) {
      const int d0 = kc * 32 + lg * 8;
      f32x4 a = *(const f32x4*)(qp + d0);
      f32x4 b = *(const f32x4*)(qp + d0 + 4);
      bf16x8 f;
      f[0] = f2bf_hw(a[0] * scale); f[1] = f2bf_hw(a[1] * scale);
      f[2] = f2bf_hw(a[2] * scale); f[3] = f2bf_hw(a[3] * scale);
      f[4] = f2bf_hw(b[0] * scale); f[5] = f2bf_hw(b[1] * scale);
      f[6] = f2bf_hw(b[2] * scale); f[7] = f2bf_hw(b[3] * scale);
      qa[m][kc] = f;
    }
  }

  // oa[m][nd][r] = O[q-row = lg*4+r (of m-tile)][d = nd*16+l15]
  f32x4 oa[2][8];
  #pragma unroll
  for (int m = 0; m < 2; ++m)
    #pragma unroll
    for (int i = 0; i < 8; ++i) oa[m][i] = (f32x4){0.f, 0.f, 0.f, 0.f};
  float mr[2] = {-1e30f, -1e30f};   // running row max, keyed q-row = l15 (row-uniform)
  float lr[2] = {0.f, 0.f};         // lane-partial row sum, keyed l15

  const char* kbase = (const char*)kbuf + ((size_t)h * NBQ << 14);
  const char* vbase = (const char*)vtbuf + ((size_t)h * NBQ << 14);

  // prologue: stage list[0] (= block 0) into buf 0
  {
    #pragma unroll
    for (int p = 0; p < 4; ++p) {
      const int ob = p * 4096 + wid * 1024;
      const int o  = ob + lane * 16;
      gload_lds16(kbase + SWK(o), lds + ob);
      gload_lds16(vbase + SWV(o), lds + 16384 + ob);
    }
  }
  __syncthreads();

  for (int t = 0; t < nlist; ++t) {
    // ---- prefetch t+1 into the other buffer ----
    if (t + 1 < nlist) {
      const int kbn = (t + 1 < nv) ? (t + 1) : (wstart + (t + 1 - nv));
      const char* ksrc = kbase + ((size_t)kbn << 14);
      const char* vsrc = vbase + ((size_t)kbn << 14);
      char* Kd = lds + ((t + 1) & 1) * 32768;
      #pragma unroll
      for (int p = 0; p < 4; ++p) {
        const int ob = p * 4096 + wid * 1024;
        const int o  = ob + lane * 16;
        gload_lds16(ksrc + SWK(o), Kd + ob);
        gload_lds16(vsrc + SWV(o), Kd + 16384 + ob);
      }
    }

    const int kb = (t < nv) ? t : (wstart + (t - nv));
    const bool valid = (kb <= qb_w) && ((qb_w - kb < 4) || (kb < 4));
    if (valid) {
      char* Kb = lds + (t & 1) * 32768;
      char* Vb = Kb + 16384;

      // ---- S^T = K Q^T : s[m][kt][r] = S[q=l15 (m-tile)][key = kt*16+lg*4+r] ----
      f32x4 s[2][4];
      #pragma unroll
      for (int m = 0; m < 2; ++m)
        #pragma unroll
        for (int kt = 0; kt < 4; ++kt) s[m][kt] = (f32x4){0.f, 0.f, 0.f, 0.f};
      __builtin_amdgcn_s_setprio(1);
      #pragma unroll
      for (int kt = 0; kt < 4; ++kt) {
        const int key = kt * 16 + l15;   // A-frag row = l15
        #pragma unroll
        for (int kc = 0; kc < 4; ++kc) {
          const int off = (key * 256 + (kc * 32 + lg * 8) * 2) ^ ((key & 7) << 4);
          bf16x8 kf = *(const bf16x8*)(Kb + off);   // A: K[key][d]
          s[0][kt] = __builtin_amdgcn_mfma_f32_16x16x32_bf16(kf, qa[0][kc], s[0][kt], 0, 0, 0);
          s[1][kt] = __builtin_amdgcn_mfma_f32_16x16x32_bf16(kf, qa[1][kc], s[1][kt], 0, 0, 0);
        }
      }
      __builtin_amdgcn_s_setprio(0);

      // ---- diagonal block: element-level causal mask (q = l15, key = kt*16+lg*4+r) ----
      if (kb == qb_w) {
        #pragma unroll
        for (int m = 0; m < 2; ++m) {
          const int rib = rib0 + m * 16 + l15;   // q-row within block
          #pragma unroll
          for (int kt = 0; kt < 4; ++kt)
            #pragma unroll
            for (int r = 0; r < 4; ++r) {
              const int key = kt * 16 + lg * 4 + r;
              if (rib < key) s[m][kt][r] = -1e30f;
            }
        }
      }

      // ---- softmax (exp2 domain, defer-max THR=8, lane-partial sum) + in-reg P + PV ----
      #pragma unroll
      for (int m = 0; m < 2; ++m) {
        float a0 = fmaxf(fmaxf(s[m][0][0], s[m][0][1]), fmaxf(s[m][0][2], s[m][0][3]));
        float a1 = fmaxf(fmaxf(s[m][1][0], s[m][1][1]), fmaxf(s[m][1][2], s[m][1][3]));
        float a2 = fmaxf(fmaxf(s[m][2][0], s[m][2][1]), fmaxf(s[m][2][2], s[m][2][3]));
        float a3 = fmaxf(fmaxf(s[m][3][0], s[m][3][1]), fmaxf(s[m][3][2], s[m][3][3]));
        float lanemax = fmaxf(fmaxf(a0, a1), fmaxf(a2, a3));
        if (!__all(lanemax <= mr[m] + 8.f)) {
          float mx = lanemax;
          mx = fmaxf(mx, __shfl_xor(mx, 16));
          mx = fmaxf(mx, __shfl_xor(mx, 32));     // row max (uniform across lg)
          const float mnew = fmaxf(mr[m], mx);
          const float sc = __builtin_amdgcn_exp2f(mr[m] - mnew);
          lr[m] *= sc;                             // lr keyed l15: direct
          mr[m] = mnew;
          // transpose sc to oa rows: row (lg*4+r)'s sc lives in lane (lg*4+r)
          const float s0 = __shfl(sc, lg * 4 + 0);
          const float s1 = __shfl(sc, lg * 4 + 1);
          const float s2 = __shfl(sc, lg * 4 + 2);
          const float s3 = __shfl(sc, lg * 4 + 3);
          #pragma unroll
          for (int nd = 0; nd < 8; ++nd) {
            oa[m][nd][0] *= s0; oa[m][nd][1] *= s1;
            oa[m][nd][2] *= s2; oa[m][nd][3] *= s3;
          }
        }
        float lsum = 0.f;
        #pragma unroll
        for (int kt = 0; kt < 4; ++kt)
          #pragma unroll
          for (int r = 0; r < 4; ++r) {
            const float p = __builtin_amdgcn_exp2f(s[m][kt][r] - mr[m]);
            s[m][kt][r] = p;
            lsum += p;
          }
        lr[m] += lsum;
      }

      // ---- pack P in-register: pa[m][kt] = A-frag (row=l15, k=lg*4+{0..3}) ----
      bf16x4 pa[2][4];
      #pragma unroll
      for (int m = 0; m < 2; ++m)
        #pragma unroll
        for (int kt = 0; kt < 4; ++kt) {
          unsigned u0 = (unsigned)(unsigned short)f2bf_hw(s[m][kt][0]) |
                        ((unsigned)(unsigned short)f2bf_hw(s[m][kt][1]) << 16);
          unsigned u1 = (unsigned)(unsigned short)f2bf_hw(s[m][kt][2]) |
                        ((unsigned)(unsigned short)f2bf_hw(s[m][kt][3]) << 16);
          uint2 uu; uu.x = u0; uu.y = u1;
          pa[m][kt] = __builtin_bit_cast(bf16x4, uu);
        }

      // ---- O += P V : 4 K-steps of 16x16x16; V b64 B-frags (keys kt*16+lg*4+{0..3}) ----
      __builtin_amdgcn_s_setprio(1);
      #pragma unroll
      for (int nd = 0; nd < 8; ++nd) {
        const int d = nd * 16 + l15;
        #pragma unroll
        for (int kt = 0; kt < 4; ++kt) {
          const int off = (d * 128 + (kt * 16 + lg * 4) * 2) ^ ((d & 7) << 4);
          bf16x4 vfr = *(const bf16x4*)(Vb + off);
          oa[0][nd] = __builtin_amdgcn_mfma_f32_16x16x16bf16_1k(pa[0][kt], vfr, oa[0][nd], 0, 0, 0);
          oa[1][nd] = __builtin_amdgcn_mfma_f32_16x16x16bf16_1k(pa[1][kt], vfr, oa[1][nd], 0, 0, 0);
        }
      }
      __builtin_amdgcn_s_setprio(0);
    }
    __syncthreads();  // drains prefetch vmcnt AND protects buffer reuse
  }

  // ---- epilogue: reduce lr (keyed l15) across lg, transpose inv to oa rows, store ----
  #pragma unroll
  for (int m = 0; m < 2; ++m) {
    float l = lr[m];
    l += __shfl_xor(l, 16);
    l += __shfl_xor(l, 32);
    const float inv = 1.0f / l;                 // keyed l15
    const float i0 = __shfl(inv, lg * 4 + 0);   // row lg*4+r's inv from lane lg*4+r
    const float i1 = __shfl(inv, lg * 4 + 1);
    const float i2 = __shfl(inv, lg * 4 + 2);
    const float i3 = __shfl(inv, lg * 4 + 3);
    float* op = outg + ((size_t)(qgrp * 128 + wid * 32 + m * 16) * HH + h) * DD;
    #pragma unroll
    for (int nd = 0; nd < 8; ++nd) {
      const int d = nd * 16 + l15;
      op[(size_t)(lg * 4 + 0) * HH * DD + d] = oa[m][nd][0] * i0;
      op[(size_t)(lg * 4 + 1) * HH * DD + d] = oa[m][nd][1] * i1;
      op[(size_t)(lg * 4 + 2) * HH * DD + d] = oa[m][nd][2] * i2;
      op[(size_t)(lg * 4 + 3) * HH * DD + d] = oa[m][nd][3] * i3;
    }
  }
}

extern "C" void kernel_launch(void* const* d_in, const int* in_sizes, int n_in,
                              void* d_out, int out_size, void* d_ws, size_t ws_size,
                              hipStream_t stream) {
  const float* q = (const float*)d_in[0];
  const float* k = (const float*)d_in[1];
  const float* v = (const float*)d_in[2];
  float* out = (float*)d_out;
  const size_t elems = (size_t)HH * SS * DD;
  unsigned short* kbuf  = (unsigned short*)d_ws;
  unsigned short* vtbuf = kbuf + elems;

  conv_k_kernel<<<(int)(elems / 4 / 256), 256, 0, stream>>>(k, kbuf);
  conv_vt_kernel<<<dim3(NBQ, HH), 256, 0, stream>>>(v, vtbuf);
  sparse_attn_v9<<<dim3(NBQ / 2, HH), 256, 65536, stream>>>(q, kbuf, vtbuf, out);
}

// Round 11
// 114.417 us; speedup vs baseline: 3.6604x; 1.0190x over previous
//
#include <hip/hip_runtime.h>
#include <hip/hip_bf16.h>

#define HH 16
#define DD 128
#define NBQ 128
#define SS 8192

typedef __attribute__((ext_vector_type(4))) float f32x4;
typedef __attribute__((ext_vector_type(4))) short bf16x4;
typedef __attribute__((ext_vector_type(8))) short bf16x8;

// single-instruction HW convert (RNE)
__device__ __forceinline__ short f2bf_hw(float f) {
  __hip_bfloat16 b = __float2bfloat16(f);
  return __builtin_bit_cast(short, b);
}

__device__ __forceinline__ void gload_lds16(const void* g, void* l) {
  __builtin_amdgcn_global_load_lds(
      (const __attribute__((address_space(1))) void*)g,
      (__attribute__((address_space(3))) void*)l, 16, 0, 0);
}

// ---------------- prepass 1: K fp32 [s][h][d] -> bf16 [h][s][d] ----------------
__global__ __launch_bounds__(256)
void conv_k_kernel(const float* __restrict__ kg, unsigned short* __restrict__ kb) {
  const size_t e = ((size_t)blockIdx.x * 256 + threadIdx.x) * 4;  // out element idx
  const int h = (int)(e >> 20);           // S*D = 2^20
  const int s = (int)((e >> 7) & (SS - 1));
  const int d = (int)(e & 127);
  f32x4 a = *(const f32x4*)(kg + ((size_t)s * HH + h) * DD + d);
  bf16x4 o;
  o[0] = f2bf_hw(a[0]); o[1] = f2bf_hw(a[1]);
  o[2] = f2bf_hw(a[2]); o[3] = f2bf_hw(a[3]);
  *(bf16x4*)(kb + e) = o;
}

// ------- prepass 2: V fp32 [s][h][d] -> bf16 transposed blocks [h][kb][d][64] -------
__global__ __launch_bounds__(256)
void conv_vt_kernel(const float* __restrict__ vg, unsigned short* __restrict__ vt) {
  __shared__ unsigned short tile[128 * 72];  // [d][s'] with +8 short pad per row
  const int kb = blockIdx.x, h = blockIdx.y, tid = threadIdx.x;
  {
    const int r = tid >> 2, q = tid & 3;
    const float* vp = vg + ((size_t)(kb * 64 + r) * HH + h) * DD + q * 32;
    #pragma unroll
    for (int c = 0; c < 8; ++c) {
      f32x4 a = *(const f32x4*)(vp + c * 4);
      #pragma unroll
      for (int j = 0; j < 4; ++j)
        tile[(q * 32 + c * 4 + j) * 72 + r] = (unsigned short)f2bf_hw(a[j]);
    }
  }
  __syncthreads();
  const int d = tid >> 1, half = tid & 1;
  unsigned short* op = vt + ((size_t)(h * NBQ + kb) * 128 + d) * 64 + half * 32;
  #pragma unroll
  for (int j = 0; j < 4; ++j)
    *(bf16x8*)(op + j * 8) = *(const bf16x8*)(&tile[d * 72 + half * 32 + j * 8]);
}

// ------------- main kernel: 1 workgroup = (2 q-blocks, head), 4 waves x 32 rows -------------
// v9-verified math (swapped QK^T, in-register P, PV via 16x16x16 K-steps).
// Structural change: 48KB LDS -> 3 workgroups/CU. K is SINGLE-buffered (consumed at iter
// start), V double-buffered (consumed at iter end). Iteration: QK -> barrier1 (K reads done,
// no vmem outstanding -> cheap) -> issue K(t+1)/V(t+1) async stages -> softmax+PV (covers
// DMA latency) -> barrier2 (drains vmcnt, protects V(t+1) buffer).
#define SWK(o) ((o) ^ ((((o) >> 8) & 7) << 4))
#define SWV(o) ((o) ^ ((((o) >> 7) & 7) << 4))

__global__ __launch_bounds__(256, 2)
void sparse_attn_v10(const float* __restrict__ qg_, const unsigned short* __restrict__ kbuf,
                     const unsigned short* __restrict__ vtbuf, float* __restrict__ outg) {
  extern __shared__ __align__(16) char lds[];
  // Ks: 0..16KB ([64 key][128 d] bf16 swz) | V buf b (b=0,1): 16384 + b*16384 ([128 d][64 key] swz)

  const int qgrp = blockIdx.x;   // 0..63
  const int h    = blockIdx.y;
  const int tid  = threadIdx.x;
  const int wid  = tid >> 6;
  const int lane = tid & 63;
  const int l15  = lane & 15;
  const int lg   = lane >> 4;

  const int qlo  = qgrp * 2, qhi = qgrp * 2 + 1;
  const int qb_w = qlo + (wid >> 1);          // this wave's q-block
  const int rib0 = (wid & 1) * 32;            // wave's row base within its q-block

  const int nv     = (qhi + 1 < 4) ? qhi + 1 : 4;
  const int wstart = (qlo - 3 > 4) ? qlo - 3 : 4;
  const int nw     = (qhi - wstart + 1 > 0) ? qhi - wstart + 1 : 0;
  const int nlist  = nv + nw;

  // 1/sqrt(128) * log2(e): exp2-domain softmax
  const float scale = 0.12752030522080552f;

  // ---- Q fragments (B operand: col j = q-row = l15, k = d = kc*32+lg*8+{0..7}) ----
  bf16x8 qa[2][4];
  #pragma unroll
  for (int m = 0; m < 2; ++m) {
    const float* qp = qg_ + ((size_t)(qgrp * 128 + wid * 32 + m * 16 + l15) * HH + h) * DD;
    #pragma unroll
    for (int kc = 0; kc < 4; ++kc) {
      const int d0 = kc * 32 + lg * 8;
      f32x4 a = *(const f32x4*)(qp + d0);
      f32x4 b = *(const f32x4*)(qp + d0 + 4);
      bf16x8 f;
      f[0] = f2bf_hw(a[0] * scale); f[1] = f2bf_hw(a[1] * scale);
      f[2] = f2bf_hw(a[2] * scale); f[3] = f2bf_hw(a[3] * scale);
      f[4] = f2bf_hw(b[0] * scale); f[5] = f2bf_hw(b[1] * scale);
      f[6] = f2bf_hw(b[2] * scale); f[7] = f2bf_hw(b[3] * scale);
      qa[m][kc] = f;
    }
  }

  // oa[m][nd][r] = O[q-row = lg*4+r (of m-tile)][d = nd*16+l15]
  f32x4 oa[2][8];
  #pragma unroll
  for (int m = 0; m < 2; ++m)
    #pragma unroll
    for (int i = 0; i < 8; ++i) oa[m][i] = (f32x4){0.f, 0.f, 0.f, 0.f};
  float mr[2] = {-1e30f, -1e30f};   // running row max, keyed q-row = l15 (row-uniform)
  float lr[2] = {0.f, 0.f};         // lane-partial row sum, keyed l15

  const char* kbase = (const char*)kbuf + ((size_t)h * NBQ << 14);
  const char* vbase = (const char*)vtbuf + ((size_t)h * NBQ << 14);

  // prologue: stage list[0] (= block 0): K -> Ks, V -> vbuf0
  {
    #pragma unroll
    for (int p = 0; p < 4; ++p) {
      const int ob = p * 4096 + wid * 1024;
      const int o  = ob + lane * 16;
      gload_lds16(kbase + SWK(o), lds + ob);
      gload_lds16(vbase + SWV(o), lds + 16384 + ob);
    }
  }
  __syncthreads();

  for (int t = 0; t < nlist; ++t) {
    const int kb = (t < nv) ? t : (wstart + (t - nv));
    const bool valid = (kb <= qb_w) && ((qb_w - kb < 4) || (kb < 4));
    char* Vb = lds + 16384 + (t & 1) * 16384;

    // ---- S^T = K Q^T : s[m][kt][r] = S[q=l15 (m-tile)][key = kt*16+lg*4+r] ----
    f32x4 s[2][4];
    if (valid) {
      #pragma unroll
      for (int m = 0; m < 2; ++m)
        #pragma unroll
        for (int kt = 0; kt < 4; ++kt) s[m][kt] = (f32x4){0.f, 0.f, 0.f, 0.f};
      __builtin_amdgcn_s_setprio(1);
      #pragma unroll
      for (int kt = 0; kt < 4; ++kt) {
        const int key = kt * 16 + l15;   // A-frag row = l15
        #pragma unroll
        for (int kc = 0; kc < 4; ++kc) {
          const int off = (key * 256 + (kc * 32 + lg * 8) * 2) ^ ((key & 7) << 4);
          bf16x8 kf = *(const bf16x8*)(lds + off);   // A: K[key][d]  (Ks at base 0)
          s[0][kt] = __builtin_amdgcn_mfma_f32_16x16x32_bf16(kf, qa[0][kc], s[0][kt], 0, 0, 0);
          s[1][kt] = __builtin_amdgcn_mfma_f32_16x16x32_bf16(kf, qa[1][kc], s[1][kt], 0, 0, 0);
        }
      }
      __builtin_amdgcn_s_setprio(0);
    }

    __syncthreads();   // barrier1: all waves done reading Ks (no vmem outstanding -> cheap)

    // ---- issue async stages for t+1: K(t+1) -> Ks (safe now), V(t+1) -> other V buf ----
    if (t + 1 < nlist) {
      const int kbn = (t + 1 < nv) ? (t + 1) : (wstart + (t + 1 - nv));
      const char* ksrc = kbase + ((size_t)kbn << 14);
      const char* vsrc = vbase + ((size_t)kbn << 14);
      char* Vd = lds + 16384 + ((t + 1) & 1) * 16384;
      #pragma unroll
      for (int p = 0; p < 4; ++p) {
        const int ob = p * 4096 + wid * 1024;
        const int o  = ob + lane * 16;
        gload_lds16(ksrc + SWK(o), lds + ob);
        gload_lds16(vsrc + SWV(o), Vd + ob);
      }
    }

    if (valid) {
      // ---- diagonal block: element-level causal mask (q = l15, key = kt*16+lg*4+r) ----
      if (kb == qb_w) {
        #pragma unroll
        for (int m = 0; m < 2; ++m) {
          const int rib = rib0 + m * 16 + l15;   // q-row within block
          #pragma unroll
          for (int kt = 0; kt < 4; ++kt)
            #pragma unroll
            for (int r = 0; r < 4; ++r) {
              const int key = kt * 16 + lg * 4 + r;
              if (rib < key) s[m][kt][r] = -1e30f;
            }
        }
      }

      // ---- softmax (exp2 domain, defer-max THR=8, lane-partial sum) ----
      #pragma unroll
      for (int m = 0; m < 2; ++m) {
        float a0 = fmaxf(fmaxf(s[m][0][0], s[m][0][1]), fmaxf(s[m][0][2], s[m][0][3]));
        float a1 = fmaxf(fmaxf(s[m][1][0], s[m][1][1]), fmaxf(s[m][1][2], s[m][1][3]));
        float a2 = fmaxf(fmaxf(s[m][2][0], s[m][2][1]), fmaxf(s[m][2][2], s[m][2][3]));
        float a3 = fmaxf(fmaxf(s[m][3][0], s[m][3][1]), fmaxf(s[m][3][2], s[m][3][3]));
        float lanemax = fmaxf(fmaxf(a0, a1), fmaxf(a2, a3));
        if (!__all(lanemax <= mr[m] + 8.f)) {
          float mx = lanemax;
          mx = fmaxf(mx, __shfl_xor(mx, 16));
          mx = fmaxf(mx, __shfl_xor(mx, 32));     // row max (uniform across lg)
          const float mnew = fmaxf(mr[m], mx);
          const float sc = __builtin_amdgcn_exp2f(mr[m] - mnew);
          lr[m] *= sc;                             // lr keyed l15: direct
          mr[m] = mnew;
          // transpose sc to oa rows: row (lg*4+r)'s sc lives in lane (lg*4+r)
          const float s0 = __shfl(sc, lg * 4 + 0);
          const float s1 = __shfl(sc, lg * 4 + 1);
          const float s2 = __shfl(sc, lg * 4 + 2);
          const float s3 = __shfl(sc, lg * 4 + 3);
          #pragma unroll
          for (int nd = 0; nd < 8; ++nd) {
            oa[m][nd][0] *= s0; oa[m][nd][1] *= s1;
            oa[m][nd][2] *= s2; oa[m][nd][3] *= s3;
          }
        }
        float lsum = 0.f;
        #pragma unroll
        for (int kt = 0; kt < 4; ++kt)
          #pragma unroll
          for (int r = 0; r < 4; ++r) {
            const float p = __builtin_amdgcn_exp2f(s[m][kt][r] - mr[m]);
            s[m][kt][r] = p;
            lsum += p;
          }
        lr[m] += lsum;
      }

      // ---- pack P in-register: pa[m][kt] = A-frag (row=l15, k=lg*4+{0..3}) ----
      bf16x4 pa[2][4];
      #pragma unroll
      for (int m = 0; m < 2; ++m)
        #pragma unroll
        for (int kt = 0; kt < 4; ++kt) {
          unsigned u0 = (unsigned)(unsigned short)f2bf_hw(s[m][kt][0]) |
                        ((unsigned)(unsigned short)f2bf_hw(s[m][kt][1]) << 16);
          unsigned u1 = (unsigned)(unsigned short)f2bf_hw(s[m][kt][2]) |
                        ((unsigned)(unsigned short)f2bf_hw(s[m][kt][3]) << 16);
          uint2 uu; uu.x = u0; uu.y = u1;
          pa[m][kt] = __builtin_bit_cast(bf16x4, uu);
        }

      // ---- O += P V : 4 K-steps of 16x16x16; V b64 B-frags (keys kt*16+lg*4+{0..3}) ----
      __builtin_amdgcn_s_setprio(1);
      #pragma unroll
      for (int nd = 0; nd < 8; ++nd) {
        const int d = nd * 16 + l15;
        #pragma unroll
        for (int kt = 0; kt < 4; ++kt) {
          const int off = (d * 128 + (kt * 16 + lg * 4) * 2) ^ ((d & 7) << 4);
          bf16x4 vfr = *(const bf16x4*)(Vb + off);
          oa[0][nd] = __builtin_amdgcn_mfma_f32_16x16x16bf16_1k(pa[0][kt], vfr, oa[0][nd], 0, 0, 0);
          oa[1][nd] = __builtin_amdgcn_mfma_f32_16x16x16bf16_1k(pa[1][kt], vfr, oa[1][nd], 0, 0, 0);
        }
      }
      __builtin_amdgcn_s_setprio(0);
    }
    __syncthreads();  // barrier2: drains K/V DMA; protects Ks (next QK) and V buffers
  }

  // ---- epilogue: reduce lr (keyed l15) across lg, transpose inv to oa rows, store ----
  #pragma unroll
  for (int m = 0; m < 2; ++m) {
    float l = lr[m];
    l += __shfl_xor(l, 16);
    l += __shfl_xor(l, 32);
    const float inv = 1.0f / l;                 // keyed l15
    const float i0 = __shfl(inv, lg * 4 + 0);   // row lg*4+r's inv from lane lg*4+r
    const float i1 = __shfl(inv, lg * 4 + 1);
    const float i2 = __shfl(inv, lg * 4 + 2);
    const float i3 = __shfl(inv, lg * 4 + 3);
    float* op = outg + ((size_t)(qgrp * 128 + wid * 32 + m * 16) * HH + h) * DD;
    #pragma unroll
    for (int nd = 0; nd < 8; ++nd) {
      const int d = nd * 16 + l15;
      op[(size_t)(lg * 4 + 0) * HH * DD + d] = oa[m][nd][0] * i0;
      op[(size_t)(lg * 4 + 1) * HH * DD + d] = oa[m][nd][1] * i1;
      op[(size_t)(lg * 4 + 2) * HH * DD + d] = oa[m][nd][2] * i2;
      op[(size_t)(lg * 4 + 3) * HH * DD + d] = oa[m][nd][3] * i3;
    }
  }
}

extern "C" void kernel_launch(void* const* d_in, const int* in_sizes, int n_in,
                              void* d_out, int out_size, void* d_ws, size_t ws_size,
                              hipStream_t stream) {
  const float* q = (const float*)d_in[0];
  const float* k = (const float*)d_in[1];
  const float* v = (const float*)d_in[2];
  float* out = (float*)d_out;
  const size_t elems = (size_t)HH * SS * DD;
  unsigned short* kbuf  = (unsigned short*)d_ws;
  unsigned short* vtbuf = kbuf + elems;

  conv_k_kernel<<<(int)(elems / 4 / 256), 256, 0, stream>>>(k, kbuf);
  conv_vt_kernel<<<dim3(NBQ, HH), 256, 0, stream>>>(v, vtbuf);
  sparse_attn_v10<<<dim3(NBQ / 2, HH), 256, 49152, stream>>>(q, kbuf, vtbuf, out);
}